// Round 5
// baseline (1288.253 us; speedup 1.0000x reference)
//
#include <hip/hip_runtime.h>
#include <hip/hip_bf16.h>
#include <math.h>

#define H 128
#define VOCAB 50000

typedef __attribute__((ext_vector_type(8))) short bf16x8;
typedef __attribute__((ext_vector_type(4))) float f32x4;

constexpr int NTOT = 131071 + 4095 + 4095;   // 139261

// fp32-path packed weights: g_pack[k][j][8]
__device__ float g_pack[128 * 128 * 8];
// MFMA packed weights, transposed [col][k'], with PERMUTED column order:
//   IOU/leaf: col c -> wg=c/96, r=c%96, ch=r/32, j=wg*32+(r&31); source col = ch*128+j
//   F:        col c -> wg=c/64, r=c%64, ch=r/32, j=wg*32+(r&31)
__device__ unsigned short g_Biou[384 * 1152];
__device__ unsigned short g_Bf[256 * 1152];
__device__ unsigned short g_Bleaf[384 * 384];
// emb pre-split to bf16: row f = [hi(128) | lo(128)]
__device__ unsigned short g_embhl[VOCAB * 256];
// global barrier state for the persistent tail kernel
__device__ unsigned g_count;
__device__ unsigned g_epoch;

struct TreeSeg { int start, cnt, hcOff, N; };

__device__ __forceinline__ float fast_sig(float x)  { return 1.0f / (1.0f + __expf(-x)); }
__device__ __forceinline__ float fast_tanh(float x) { return 1.0f - 2.0f / (__expf(2.0f * x) + 1.0f); }
__device__ __forceinline__ unsigned short f2bf(float f) {
    unsigned int u = __float_as_uint(f);
    return (unsigned short)((u + 0x7FFFu + ((u >> 16) & 1u)) >> 16);
}
__device__ __forceinline__ float bf2f(unsigned short h) {
    return __uint_as_float(((unsigned int)h) << 16);
}
__device__ __forceinline__ unsigned short bf_split(float v, bool lo) {
    unsigned short hi = f2bf(v);
    return lo ? f2bf(v - bf2f(hi)) : hi;
}

// ---------------- pack kernels ----------------
__global__ __launch_bounds__(128)
void pack_kernel(const float* __restrict__ Wiou, const float* __restrict__ Wf,
                 const float* __restrict__ Uiou, const float* __restrict__ Uf)
{
    const int k = blockIdx.x;
    const int j = threadIdx.x;
    float4 a, b;
    a.x = Wiou[k * 384 + j];
    a.y = Wiou[k * 384 + 128 + j];
    a.z = Wiou[k * 384 + 256 + j];
    a.w = Wf[k * 128 + j];
    b.x = Uiou[k * 384 + j];
    b.y = Uiou[k * 384 + 128 + j];
    b.z = Uiou[k * 384 + 256 + j];
    b.w = Uf[k * 128 + j];
    float4* o = reinterpret_cast<float4*>(g_pack + ((size_t)k * 128 + j) * 8);
    o[0] = a;
    o[1] = b;
}

__global__ __launch_bounds__(256)
void pack_B(const float* __restrict__ Wiou, const float* __restrict__ Uiou,
            const float* __restrict__ Wf, const float* __restrict__ Uf)
{
    const int NB1 = 384 * 1152, NB2 = NB1 + 256 * 1152, NB3 = NB2 + 384 * 384;
    int idx = blockIdx.x * 256 + threadIdx.x;
    if (idx < NB1) {
        int c = idx / 1152, k = idx % 1152;
        int wg = c / 96, r = c % 96, ch = r / 32, jj = wg * 32 + (r & 31);
        int srccol = ch * 128 + jj;
        int kb = k % 384; bool lo = k >= 768;
        float v = (kb < 128) ? Wiou[kb * 384 + srccol] : Uiou[((kb - 128) & 127) * 384 + srccol];
        g_Biou[c * 1152 + k] = bf_split(v, lo);
    } else if (idx < NB2) {
        int rr = idx - NB1;
        int c = rr / 1152, k = rr % 1152;
        int wg = c / 64, r = c % 64, ch = r / 32, jj = wg * 32 + (r & 31);
        int kb = k % 384; bool lo = k >= 768;
        float v;
        if (kb < 128)      v = Wf[kb * 128 + jj];
        else if (kb < 256) v = (ch == 0) ? Uf[(kb - 128) * 128 + jj] : 0.0f;
        else               v = (ch == 1) ? Uf[(kb - 256) * 128 + jj] : 0.0f;
        g_Bf[c * 1152 + k] = bf_split(v, lo);
    } else if (idx < NB3) {
        int rr = idx - NB2;
        int c = rr / 384, k = rr % 384;
        int wg = c / 96, r = c % 96, ch = r / 32, jj = wg * 32 + (r & 31);
        int srccol = ch * 128 + jj;
        int kb = k % 128; bool lo = k >= 256;
        g_Bleaf[c * 384 + k] = bf_split(Wiou[kb * 384 + srccol], lo);
    }
}

__global__ __launch_bounds__(256)
void pack_emb(const float* __restrict__ emb)
{
    int idx = blockIdx.x * 256 + threadIdx.x;
    if (idx >= VOCAB * 32) return;
    const int f = idx >> 5, k4 = idx & 31;
    float4 v = reinterpret_cast<const float4*>(emb + (size_t)f * 128)[k4];
    const float fv[4] = {v.x, v.y, v.z, v.w};
    ushort4 hi4, lo4;
    unsigned short* hp = reinterpret_cast<unsigned short*>(&hi4);
    unsigned short* lp = reinterpret_cast<unsigned short*>(&lo4);
    #pragma unroll
    for (int t = 0; t < 4; ++t) {
        unsigned short hb = f2bf(fv[t]);
        hp[t] = hb;
        lp[t] = f2bf(fv[t] - bf2f(hb));
    }
    *reinterpret_cast<ushort4*>(g_embhl + (size_t)f * 256 + k4 * 4) = hi4;
    *reinterpret_cast<ushort4*>(g_embhl + (size_t)f * 256 + 128 + k4 * 4) = lo4;
}

__global__ void reset_bar() { g_count = 0; g_epoch = 0; }

// ---------------- MFMA level GEMM ----------------
// 128-row blocks, 8 waves (2m x 4n), wave tile 64 x (NCOL/4).
// Double-buffered LDS, ONE barrier per kt.
// MODE 0 = F (256 cols), 1 = IOU (384), 2 = leaf IOU (384, K'=384)
template<int MODE>
__global__ __launch_bounds__(512, 2)
void gemm_level(const int* __restrict__ feat0, const int* __restrict__ feat1,
                const int* __restrict__ feat2,
                const unsigned short* __restrict__ hhi, const unsigned short* __restrict__ hlo,
                unsigned short* __restrict__ whhi, unsigned short* __restrict__ whlo,
                float* __restrict__ cbuf,
                const float* __restrict__ b_iou, const float* __restrict__ b_f,
                TreeSeg s0, TreeSeg s1, TreeSeg s2, int blocks0, int blocks01)
{
    constexpr int KT   = (MODE == 2) ? 6 : 18;
    constexpr int KP   = (MODE == 2) ? 384 : 1152;
    constexpr int NCOL = (MODE == 0) ? 256 : 384;
    constexpr int NBC  = NCOL / 64;     // B staging chunks (4 or 6)
    constexpr int NFC  = NCOL / 64;     // B frags per wave per slice (4 or 6)
    __shared__ unsigned short Als[2][128 * 64];
    __shared__ unsigned short Bls[2][NCOL * 64];

    const int bid = blockIdx.x;
    TreeSeg seg; const int* feat; int batch;
    if (bid < blocks0)       { seg = s0; feat = feat0; batch = bid; }
    else if (bid < blocks01) { seg = s1; feat = feat1; batch = bid - blocks0; }
    else                     { seg = s2; feat = feat2; batch = bid - blocks01; }

    const int tid = threadIdx.x;
    const int nbase = seg.start + batch * 128;

    // A staging: 2 chunks per thread (rows tid>>3 and 64+tid>>3, slot tid&7)
    const unsigned short* erow[2];
    const unsigned short* hrhi[2];
    const unsigned short* hrlo[2];
    int adst[2];
    #pragma unroll
    for (int c = 0; c < 2; ++c) {
        const int id = c * 512 + tid;
        const int row = id >> 3, slot = id & 7;
        const int node = nbase + row;
        erow[c] = g_embhl + (size_t)feat[node] * 256 + slot * 8;
        if (MODE != 2) {
            const size_t hbase = (size_t)(seg.hcOff + 2 * node - seg.N - 1) * 128 + slot * 8;
            hrhi[c] = hhi + hbase;
            hrlo[c] = hlo + hbase;
        }
        adst[c] = row * 64 + ((slot ^ (row & 7)) << 3);
    }

    const unsigned short* BT = (MODE == 0) ? g_Bf : ((MODE == 2) ? g_Bleaf : g_Biou);
    const unsigned short* bsrc[NBC];
    int bdst[NBC];
    #pragma unroll
    for (int it = 0; it < NBC; ++it) {
        const int id = it * 512 + tid;
        const int col = id >> 3, slot = id & 7;
        bsrc[it] = BT + (size_t)col * KP + slot * 8;
        bdst[it] = col * 64 + ((slot ^ (col & 7)) << 3);
    }

    auto loadA = [&](int kt, int c) -> bf16x8 {
        if (MODE == 2) {
            const int off = (((kt >> 1) == 1) ? 128 : 0) + (kt & 1) * 64;
            return *reinterpret_cast<const bf16x8*>(erow[c] + off);
        } else {
            const int p = (kt >= 12) ? 2 : (kt >= 6 ? 1 : 0);
            const int ktm = kt - p * 6;
            const bool lo = (p == 1);
            if (ktm < 2)
                return *reinterpret_cast<const bf16x8*>(erow[c] + (lo ? 128 : 0) + ktm * 64);
            const unsigned short* hp = lo ? hrlo[c] : hrhi[c];
            return *reinterpret_cast<const bf16x8*>(hp + (ktm - 2) * 64);
        }
    };

    f32x4 acc[4][NFC];
    #pragma unroll
    for (int a = 0; a < 4; ++a)
        #pragma unroll
        for (int b = 0; b < NFC; ++b) acc[a][b] = (f32x4){0.f, 0.f, 0.f, 0.f};

    const int lane = tid & 63;
    const int wv = tid >> 6;
    const int wm = wv >> 2, wn = wv & 3;
    const int l15 = lane & 15, l4 = lane >> 4;

    // prologue: fetch kt=0 into regs
    bf16x8 aR0 = loadA(0, 0), aR1 = loadA(0, 1);
    bf16x8 bR[NBC];
    #pragma unroll
    for (int it = 0; it < NBC; ++it)
        bR[it] = *reinterpret_cast<const bf16x8*>(bsrc[it]);

    int cur = 0;
    for (int kt = 0; kt < KT; ++kt) {
        *reinterpret_cast<bf16x8*>(&Als[cur][adst[0]]) = aR0;
        *reinterpret_cast<bf16x8*>(&Als[cur][adst[1]]) = aR1;
        #pragma unroll
        for (int it = 0; it < NBC; ++it)
            *reinterpret_cast<bf16x8*>(&Bls[cur][bdst[it]]) = bR[it];
        if (kt + 1 < KT) {
            aR0 = loadA(kt + 1, 0);
            aR1 = loadA(kt + 1, 1);
            #pragma unroll
            for (int it = 0; it < NBC; ++it)
                bR[it] = *reinterpret_cast<const bf16x8*>(bsrc[it] + (size_t)(kt + 1) * 64);
        }
        __syncthreads();
        #pragma unroll
        for (int st = 0; st < 2; ++st) {
            const int q = st * 4 + l4;
            bf16x8 af[4];
            #pragma unroll
            for (int fm = 0; fm < 4; ++fm) {
                const int row = wm * 64 + fm * 16 + l15;
                af[fm] = *reinterpret_cast<const bf16x8*>(&Als[cur][row * 64 + ((q ^ (row & 7)) << 3)]);
            }
            #pragma unroll
            for (int fc = 0; fc < NFC; ++fc) {
                const int col = wn * (NCOL / 4) + fc * 16 + l15;
                const bf16x8 bfr = *reinterpret_cast<const bf16x8*>(&Bls[cur][col * 64 + ((q ^ (col & 7)) << 3)]);
                #pragma unroll
                for (int fm = 0; fm < 4; ++fm)
                    acc[fm][fc] = __builtin_amdgcn_mfma_f32_16x16x32_bf16(af[fm], bfr, acc[fm][fc], 0, 0, 0);
            }
        }
        cur ^= 1;
        // no trailing barrier: next iteration stores into the other buffer;
        // same-buffer reuse is 2 iterations away, gated by the next barrier.
    }

    // ---- fused epilogue (gate-mates are same-lane: fc, fc+2, fc+4) ----
    #pragma unroll
    for (int fcL = 0; fcL < 2; ++fcL) {
        const int j = wn * 32 + fcL * 16 + l15;
        if constexpr (MODE == 0) {
            const float bff = b_f[j];
            #pragma unroll
            for (int fm = 0; fm < 4; ++fm) {
                #pragma unroll
                for (int r = 0; r < 4; ++r) {
                    const int node = nbase + wm * 64 + fm * 16 + l4 * 4 + r;
                    const size_t crow = (size_t)(seg.hcOff + node) * 128;
                    const size_t cbase = (size_t)(seg.hcOff + 2 * node - seg.N - 1) * 128;
                    const float fa = fast_sig(acc[fm][fcL][r] + bff);
                    const float fb = fast_sig(acc[fm][fcL + 2][r] + bff);
                    cbuf[crow + j] = fa * cbuf[cbase + j] + fb * cbuf[cbase + 128 + j];
                }
            }
        } else {
            const float bi = b_iou[j];
            const float bo = b_iou[128 + j];
            const float bu = b_iou[256 + j];
            #pragma unroll
            for (int fm = 0; fm < 4; ++fm) {
                #pragma unroll
                for (int r = 0; r < 4; ++r) {
                    const int node = nbase + wm * 64 + fm * 16 + l4 * 4 + r;
                    const size_t crow = (size_t)(seg.hcOff + node) * 128;
                    const float iv = fast_sig(acc[fm][fcL][r] + bi);
                    const float ov = fast_sig(acc[fm][fcL + 2][r] + bo);
                    const float uv = fast_tanh(acc[fm][fcL + 4][r] + bu);
                    float cn = iv * uv;
                    if (MODE == 1) cn += cbuf[crow + j];
                    cbuf[crow + j] = cn;
                    const float hn = ov * fast_tanh(cn);
                    const unsigned short hi16 = f2bf(hn);
                    whhi[crow + j] = hi16;
                    whlo[crow + j] = f2bf(hn - bf2f(hi16));
                }
            }
        }
    }
}

// ---------------- persistent fp32 tail: levels 4..16, one dispatch ----------------
__device__ __forceinline__ void grid_bar(int nb, unsigned e)
{
    __syncthreads();
    if (threadIdx.x == 0) {
        __threadfence();   // release: write back this XCD's dirty L2 lines
        const unsigned prev = atomicAdd(&g_count, 1u);
        if (prev == (unsigned)(nb - 1)) {
            g_count = 0;
            __threadfence();
            atomicExch(&g_epoch, e);
        } else {
            while (atomicAdd(&g_epoch, 0u) < e) {}
        }
        __threadfence();   // acquire: invalidate stale L2 lines
    }
    __syncthreads();
}

__global__ __launch_bounds__(128)
void tail_kernel(const float* __restrict__ emb,
                 const float* __restrict__ b_iou, const float* __restrict__ b_f,
                 const int* __restrict__ feat0, const int* __restrict__ feat1,
                 const int* __restrict__ feat2,
                 unsigned short* __restrict__ hhi, unsigned short* __restrict__ hlo,
                 float* __restrict__ cbuf)
{
    __shared__ float xe[16][128];
    __shared__ float ha[16][128];
    __shared__ float hb[16][128];

    const int Dt[3] = {17, 12, 12};
    const int Nt[3] = {131071, 4095, 4095};
    const int off[3] = {0, 131071, 131071 + 4095};
    const int tid = threadIdx.x;
    unsigned epoch = 0;

    for (int l = 4; l <= 16; ++l) {
        int cnt[3], st[3], chk[3];
        #pragma unroll
        for (int t = 0; t < 3; ++t) {
            if (l <= Dt[t] - 1) {
                cnt[t] = 1 << (Dt[t] - 1 - l);
                st[t]  = Nt[t] - (1 << (Dt[t] - l)) + 1;
            } else { cnt[t] = 0; st[t] = 0; }
            chk[t] = (cnt[t] + 15) >> 4;
        }
        const int tot = chk[0] + chk[1] + chk[2];

        for (int ci = blockIdx.x; ci < tot; ci += gridDim.x) {
            int t, batch;
            if (ci < chk[0])            { t = 0; batch = ci; }
            else if (ci < chk[0] + chk[1]) { t = 1; batch = ci - chk[0]; }
            else                        { t = 2; batch = ci - chk[0] - chk[1]; }
            const int* feat = (t == 0) ? feat0 : ((t == 1) ? feat1 : feat2);
            const int nbase = st[t] + batch * 16;
            const int nval  = min(16, st[t] + cnt[t] - nbase);
            const int hcOff = off[t];
            const int Ntree = Nt[t];

            // stage x, h_childA, h_childB
            for (int idx = tid; idx < 16 * 32; idx += 128) {
                const int n  = idx >> 5;
                const int k4 = idx & 31;
                const int node = nbase + min(n, nval - 1);
                const int f = feat[node];
                float4 v = reinterpret_cast<const float4*>(emb + (size_t)f * 128)[k4];
                *reinterpret_cast<float4*>(&xe[n][k4 * 4]) = v;
                const int a = 2 * node - Ntree - 1;
                const size_t ra = (size_t)(hcOff + a) * 128 + k4 * 4;
                ushort4 h4 = *reinterpret_cast<const ushort4*>(hhi + ra);
                ushort4 l4v = *reinterpret_cast<const ushort4*>(hlo + ra);
                float4 va;
                va.x = bf2f(h4.x) + bf2f(l4v.x);
                va.y = bf2f(h4.y) + bf2f(l4v.y);
                va.z = bf2f(h4.z) + bf2f(l4v.z);
                va.w = bf2f(h4.w) + bf2f(l4v.w);
                *reinterpret_cast<float4*>(&ha[n][k4 * 4]) = va;
                ushort4 h4b = *reinterpret_cast<const ushort4*>(hhi + ra + 128);
                ushort4 l4b = *reinterpret_cast<const ushort4*>(hlo + ra + 128);
                float4 vb;
                vb.x = bf2f(h4b.x) + bf2f(l4b.x);
                vb.y = bf2f(h4b.y) + bf2f(l4b.y);
                vb.z = bf2f(h4b.z) + bf2f(l4b.z);
                vb.w = bf2f(h4b.w) + bf2f(l4b.w);
                *reinterpret_cast<float4*>(&hb[n][k4 * 4]) = vb;
            }
            __syncthreads();

            const int j = tid;
            float ai[16], ao[16], au[16], axf[16], afa[16], afb[16];
            {
                const float bi = b_iou[j];
                const float bo = b_iou[128 + j];
                const float bu = b_iou[256 + j];
                const float bff = b_f[j];
                #pragma unroll
                for (int n = 0; n < 16; ++n) {
                    ai[n] = bi; ao[n] = bo; au[n] = bu;
                    axf[n] = bff; afa[n] = 0.0f; afb[n] = 0.0f;
                }
            }
            const float* pkj = g_pack + (size_t)j * 8;
            for (int kk = 0; kk < 32; ++kk) {
                float4 wa[4], wb[4];
                #pragma unroll
                for (int r = 0; r < 4; ++r) {
                    const float* p = pkj + (size_t)(kk * 4 + r) * 1024;
                    wa[r] = *reinterpret_cast<const float4*>(p);
                    wb[r] = *reinterpret_cast<const float4*>(p + 4);
                }
                #pragma unroll
                for (int n = 0; n < 16; ++n) {
                    const float4 xv = *reinterpret_cast<const float4*>(&xe[n][kk * 4]);
                    const float4 av = *reinterpret_cast<const float4*>(&ha[n][kk * 4]);
                    const float4 bv = *reinterpret_cast<const float4*>(&hb[n][kk * 4]);
                    const float xs[4] = {xv.x, xv.y, xv.z, xv.w};
                    const float as[4] = {av.x, av.y, av.z, av.w};
                    const float bs[4] = {bv.x, bv.y, bv.z, bv.w};
                    #pragma unroll
                    for (int r = 0; r < 4; ++r) {
                        const float hs = as[r] + bs[r];
                        ai[n]  = fmaf(xs[r], wa[r].x, ai[n]);
                        ao[n]  = fmaf(xs[r], wa[r].y, ao[n]);
                        au[n]  = fmaf(xs[r], wa[r].z, au[n]);
                        ai[n]  = fmaf(hs,    wb[r].x, ai[n]);
                        ao[n]  = fmaf(hs,    wb[r].y, ao[n]);
                        au[n]  = fmaf(hs,    wb[r].z, au[n]);
                        axf[n] = fmaf(xs[r], wa[r].w, axf[n]);
                        afa[n] = fmaf(as[r], wb[r].w, afa[n]);
                        afb[n] = fmaf(bs[r], wb[r].w, afb[n]);
                    }
                }
            }
            #pragma unroll
            for (int n = 0; n < 16; ++n) {
                if (n >= nval) break;
                const int node = nbase + n;
                const float iv = fast_sig(ai[n]);
                const float ov = fast_sig(ao[n]);
                const float uv = fast_tanh(au[n]);
                const float fav = fast_sig(axf[n] + afa[n]);
                const float fbv = fast_sig(axf[n] + afb[n]);
                const int a = 2 * node - Ntree - 1;
                const float ca  = cbuf[(size_t)(hcOff + a) * 128 + j];
                const float cb2 = cbuf[(size_t)(hcOff + a + 1) * 128 + j];
                const float cn = fmaf(fav, ca, fmaf(fbv, cb2, iv * uv));
                const float hn = ov * fast_tanh(cn);
                const size_t o = (size_t)(hcOff + node) * 128 + j;
                cbuf[o] = cn;
                const unsigned short hi16 = f2bf(hn);
                hhi[o] = hi16;
                hlo[o] = f2bf(hn - bf2f(hi16));
            }
            __syncthreads();   // before re-staging LDS for the next chunk
        }
        if (l < 16) grid_bar(gridDim.x, ++epoch);
    }
}

// fuse_a_b @ h_c == h_a * dot(h_b, h_c); then 2-layer MLP with ReLU.
__global__ __launch_bounds__(128)
void final_kernel(const unsigned short* __restrict__ hhi, const unsigned short* __restrict__ hlo,
                  const float* __restrict__ fc1_w, const float* __restrict__ fc1_b,
                  const float* __restrict__ fc2_w, const float* __restrict__ fc2_b,
                  float* __restrict__ out,
                  int rc, int ra, int rb)
{
    __shared__ float sh[128];
    __shared__ float z1[64];
    __shared__ float dots[2];
    const int tid = threadIdx.x;

    const float hc  = bf2f(hhi[(size_t)rc * H + tid]) + bf2f(hlo[(size_t)rc * H + tid]);
    const float hav = bf2f(hhi[(size_t)ra * H + tid]) + bf2f(hlo[(size_t)ra * H + tid]);
    const float hbv = bf2f(hhi[(size_t)rb * H + tid]) + bf2f(hlo[(size_t)rb * H + tid]);

    float p = hbv * hc;
    #pragma unroll
    for (int o = 32; o > 0; o >>= 1) p += __shfl_down(p, o);
    if ((tid & 63) == 0) dots[tid >> 6] = p;
    __syncthreads();
    const float dot = dots[0] + dots[1];
    sh[tid] = hav * dot;
    __syncthreads();

    if (tid < 64) {
        float z = fc1_b[tid];
        for (int i = 0; i < 128; ++i) z = fmaf(sh[i], fc1_w[i * 64 + tid], z);
        z1[tid] = fmaxf(z, 0.0f);
    }
    __syncthreads();
    if (tid < 3) {
        float z = fc2_b[tid];
        for (int jj = 0; jj < 64; ++jj) z = fmaf(z1[jj], fc2_w[jj * 3 + tid], z);
        out[tid] = fmaxf(z, 0.0f);
    }
}

extern "C" void kernel_launch(void* const* d_in, const int* in_sizes, int n_in,
                              void* d_out, int out_size, void* d_ws, size_t ws_size,
                              hipStream_t stream) {
    const float* emb   = (const float*)d_in[12];
    const float* W_iou = (const float*)d_in[13];
    const float* b_iou = (const float*)d_in[14];
    const float* U_iou = (const float*)d_in[15];
    const float* W_f   = (const float*)d_in[16];
    const float* b_f   = (const float*)d_in[17];
    const float* U_f   = (const float*)d_in[18];
    const float* fc1_w = (const float*)d_in[19];
    const float* fc1_b = (const float*)d_in[20];
    const float* fc2_w = (const float*)d_in[21];
    const float* fc2_b = (const float*)d_in[22];
    const int* feats[3] = { (const int*)d_in[0], (const int*)d_in[4], (const int*)d_in[8] };

    const int D[3] = {17, 12, 12};
    const int N[3] = {131071, 4095, 4095};
    const int off[3] = {0, 131071, 131071 + 4095};

    float* cbuf = (float*)d_ws;
    unsigned short* hhi = (unsigned short*)(cbuf + (size_t)NTOT * 128);
    unsigned short* hlo = hhi + (size_t)NTOT * 128;

    pack_kernel<<<128, 128, 0, stream>>>(W_iou, W_f, U_iou, U_f);
    {
        const int NB3 = 384 * 1152 + 256 * 1152 + 384 * 384;
        pack_B<<<(NB3 + 255) / 256, 256, 0, stream>>>(W_iou, U_iou, W_f, U_f);
    }
    pack_emb<<<(VOCAB * 32 + 255) / 256, 256, 0, stream>>>(emb);
    reset_bar<<<1, 1, 0, stream>>>();

    auto mkseg = [&](int l, int t) {
        TreeSeg s;
        if (l <= D[t] - 1) {
            s.cnt   = 1 << (D[t] - 1 - l);
            s.start = N[t] - (1 << (D[t] - l)) + 1;
        } else { s.cnt = 0; s.start = 0; }
        s.hcOff = off[t]; s.N = N[t];
        return s;
    };

    // ---- leaf level (l=0): MFMA IOU-leaf, 128-row blocks ----
    {
        TreeSeg s0 = mkseg(0, 0), s1 = mkseg(0, 1), s2 = mkseg(0, 2);
        int b0 = s0.cnt / 128, b1 = s1.cnt / 128, b2 = s2.cnt / 128;
        gemm_level<2><<<b0 + b1 + b2, 512, 0, stream>>>(
            feats[0], feats[1], feats[2], hhi, hlo, hhi, hlo, cbuf,
            b_iou, b_f, s0, s1, s2, b0, b0 + b1);
    }

    // ---- levels 1..3: MFMA F then IOU ----
    for (int l = 1; l <= 3; ++l) {
        TreeSeg s0 = mkseg(l, 0), s1 = mkseg(l, 1), s2 = mkseg(l, 2);
        int b0 = s0.cnt / 128, b1 = s1.cnt / 128, b2 = s2.cnt / 128;
        const int total = b0 + b1 + b2;
        gemm_level<0><<<total, 512, 0, stream>>>(
            feats[0], feats[1], feats[2], hhi, hlo, hhi, hlo, cbuf,
            b_iou, b_f, s0, s1, s2, b0, b0 + b1);
        gemm_level<1><<<total, 512, 0, stream>>>(
            feats[0], feats[1], feats[2], hhi, hlo, hhi, hlo, cbuf,
            b_iou, b_f, s0, s1, s2, b0, b0 + b1);
    }

    // ---- levels 4..16: single persistent fp32 kernel with grid barrier ----
    tail_kernel<<<256, 128, 0, stream>>>(emb, b_iou, b_f,
                                         feats[0], feats[1], feats[2],
                                         hhi, hlo, cbuf);

    const int rc = off[0] + N[0] - 1;
    const int ra = off[1] + N[1] - 1;
    const int rb = off[2] + N[2] - 1;
    final_kernel<<<1, 128, 0, stream>>>(hhi, hlo, fc1_w, fc1_b, fc2_w, fc2_b,
                                        (float*)d_out, rc, ra, rb);
}

// Round 6
// 813.823 us; speedup vs baseline: 1.5830x; 1.5830x over previous
//
#include <hip/hip_runtime.h>
#include <hip/hip_bf16.h>
#include <math.h>

#define H 128
#define VOCAB 50000

typedef __attribute__((ext_vector_type(8))) short bf16x8;
typedef __attribute__((ext_vector_type(4))) float f32x4;

constexpr int NTOT = 131071 + 4095 + 4095;   // 139261

// fp32-path packed weights: g_pack[k][j][8]
__device__ float g_pack[128 * 128 * 8];
// MFMA packed weights, transposed [col][k'], with PERMUTED column order:
//   IOU/leaf: col c -> wg=c/96, r=c%96, ch=r/32, j=wg*32+(r&31); source col = ch*128+j
//   F:        col c -> wg=c/64, r=c%64, ch=r/32, j=wg*32+(r&31)
__device__ unsigned short g_Biou[384 * 1152];
__device__ unsigned short g_Bf[256 * 1152];
__device__ unsigned short g_Bleaf[384 * 384];
// emb pre-split to bf16: row f = [hi(128) | lo(128)]
__device__ unsigned short g_embhl[VOCAB * 256];

struct TreeSeg { int start, cnt, hcOff, N; };

__device__ __forceinline__ float fast_sig(float x)  { return 1.0f / (1.0f + __expf(-x)); }
__device__ __forceinline__ float fast_tanh(float x) { return 1.0f - 2.0f / (__expf(2.0f * x) + 1.0f); }
__device__ __forceinline__ unsigned short f2bf(float f) {
    unsigned int u = __float_as_uint(f);
    return (unsigned short)((u + 0x7FFFu + ((u >> 16) & 1u)) >> 16);
}
__device__ __forceinline__ float bf2f(unsigned short h) {
    return __uint_as_float(((unsigned int)h) << 16);
}
__device__ __forceinline__ unsigned short bf_split(float v, bool lo) {
    unsigned short hi = f2bf(v);
    return lo ? f2bf(v - bf2f(hi)) : hi;
}

// ---------------- pack kernels ----------------
__global__ __launch_bounds__(128)
void pack_kernel(const float* __restrict__ Wiou, const float* __restrict__ Wf,
                 const float* __restrict__ Uiou, const float* __restrict__ Uf)
{
    const int k = blockIdx.x;
    const int j = threadIdx.x;
    float4 a, b;
    a.x = Wiou[k * 384 + j];
    a.y = Wiou[k * 384 + 128 + j];
    a.z = Wiou[k * 384 + 256 + j];
    a.w = Wf[k * 128 + j];
    b.x = Uiou[k * 384 + j];
    b.y = Uiou[k * 384 + 128 + j];
    b.z = Uiou[k * 384 + 256 + j];
    b.w = Uf[k * 128 + j];
    float4* o = reinterpret_cast<float4*>(g_pack + ((size_t)k * 128 + j) * 8);
    o[0] = a;
    o[1] = b;
}

__global__ __launch_bounds__(256)
void pack_B(const float* __restrict__ Wiou, const float* __restrict__ Uiou,
            const float* __restrict__ Wf, const float* __restrict__ Uf)
{
    const int NB1 = 384 * 1152, NB2 = NB1 + 256 * 1152, NB3 = NB2 + 384 * 384;
    int idx = blockIdx.x * 256 + threadIdx.x;
    if (idx < NB1) {
        int c = idx / 1152, k = idx % 1152;
        int wg = c / 96, r = c % 96, ch = r / 32, jj = wg * 32 + (r & 31);
        int srccol = ch * 128 + jj;
        int kb = k % 384; bool lo = k >= 768;
        float v = (kb < 128) ? Wiou[kb * 384 + srccol] : Uiou[((kb - 128) & 127) * 384 + srccol];
        g_Biou[c * 1152 + k] = bf_split(v, lo);
    } else if (idx < NB2) {
        int rr = idx - NB1;
        int c = rr / 1152, k = rr % 1152;
        int wg = c / 64, r = c % 64, ch = r / 32, jj = wg * 32 + (r & 31);
        int kb = k % 384; bool lo = k >= 768;
        float v;
        if (kb < 128)      v = Wf[kb * 128 + jj];
        else if (kb < 256) v = (ch == 0) ? Uf[(kb - 128) * 128 + jj] : 0.0f;
        else               v = (ch == 1) ? Uf[(kb - 256) * 128 + jj] : 0.0f;
        g_Bf[c * 1152 + k] = bf_split(v, lo);
    } else if (idx < NB3) {
        int rr = idx - NB2;
        int c = rr / 384, k = rr % 384;
        int wg = c / 96, r = c % 96, ch = r / 32, jj = wg * 32 + (r & 31);
        int srccol = ch * 128 + jj;
        int kb = k % 128; bool lo = k >= 256;
        g_Bleaf[c * 384 + k] = bf_split(Wiou[kb * 384 + srccol], lo);
    }
}

__global__ __launch_bounds__(256)
void pack_emb(const float* __restrict__ emb)
{
    int idx = blockIdx.x * 256 + threadIdx.x;
    if (idx >= VOCAB * 32) return;
    const int f = idx >> 5, k4 = idx & 31;
    float4 v = reinterpret_cast<const float4*>(emb + (size_t)f * 128)[k4];
    const float fv[4] = {v.x, v.y, v.z, v.w};
    ushort4 hi4, lo4;
    unsigned short* hp = reinterpret_cast<unsigned short*>(&hi4);
    unsigned short* lp = reinterpret_cast<unsigned short*>(&lo4);
    #pragma unroll
    for (int t = 0; t < 4; ++t) {
        unsigned short hb = f2bf(fv[t]);
        hp[t] = hb;
        lp[t] = f2bf(fv[t] - bf2f(hb));
    }
    *reinterpret_cast<ushort4*>(g_embhl + (size_t)f * 256 + k4 * 4) = hi4;
    *reinterpret_cast<ushort4*>(g_embhl + (size_t)f * 256 + 128 + k4 * 4) = lo4;
}

// ---------------- MFMA level GEMM ----------------
// 128-row blocks (masked for partial), 8 waves (2m x 4n), double-buffered LDS,
// ONE barrier per kt. MODE 0 = F (256 cols), 1 = IOU (384), 2 = leaf IOU (384, K'=384)
template<int MODE>
__global__ __launch_bounds__(512, 2)
void gemm_level(const int* __restrict__ feat0, const int* __restrict__ feat1,
                const int* __restrict__ feat2,
                const unsigned short* __restrict__ hhi, const unsigned short* __restrict__ hlo,
                unsigned short* __restrict__ whhi, unsigned short* __restrict__ whlo,
                float* __restrict__ cbuf,
                const float* __restrict__ b_iou, const float* __restrict__ b_f,
                TreeSeg s0, TreeSeg s1, TreeSeg s2, int blocks0, int blocks01)
{
    constexpr int KT   = (MODE == 2) ? 6 : 18;
    constexpr int KP   = (MODE == 2) ? 384 : 1152;
    constexpr int NCOL = (MODE == 0) ? 256 : 384;
    constexpr int NBC  = NCOL / 64;
    constexpr int NFC  = NCOL / 64;
    __shared__ unsigned short Als[2][128 * 64];
    __shared__ unsigned short Bls[2][NCOL * 64];

    const int bid = blockIdx.x;
    TreeSeg seg; const int* feat; int batch;
    if (bid < blocks0)       { seg = s0; feat = feat0; batch = bid; }
    else if (bid < blocks01) { seg = s1; feat = feat1; batch = bid - blocks0; }
    else                     { seg = s2; feat = feat2; batch = bid - blocks01; }

    const int tid = threadIdx.x;
    const int nbase = seg.start + batch * 128;
    const int vrows = min(128, seg.cnt - batch * 128);   // valid rows in this block

    // A staging: 2 chunks per thread; clamp rows beyond vrows to a valid node
    const unsigned short* erow[2];
    const unsigned short* hrhi[2];
    const unsigned short* hrlo[2];
    int adst[2];
    #pragma unroll
    for (int c = 0; c < 2; ++c) {
        const int id = c * 512 + tid;
        const int row = id >> 3, slot = id & 7;
        const int node = nbase + min(row, vrows - 1);
        erow[c] = g_embhl + (size_t)feat[node] * 256 + slot * 8;
        if (MODE != 2) {
            const size_t hbase = (size_t)(seg.hcOff + 2 * node - seg.N - 1) * 128 + slot * 8;
            hrhi[c] = hhi + hbase;
            hrlo[c] = hlo + hbase;
        }
        adst[c] = row * 64 + ((slot ^ (row & 7)) << 3);
    }

    const unsigned short* BT = (MODE == 0) ? g_Bf : ((MODE == 2) ? g_Bleaf : g_Biou);
    const unsigned short* bsrc[NBC];
    int bdst[NBC];
    #pragma unroll
    for (int it = 0; it < NBC; ++it) {
        const int id = it * 512 + tid;
        const int col = id >> 3, slot = id & 7;
        bsrc[it] = BT + (size_t)col * KP + slot * 8;
        bdst[it] = col * 64 + ((slot ^ (col & 7)) << 3);
    }

    auto loadA = [&](int kt, int c) -> bf16x8 {
        if (MODE == 2) {
            const int off = (((kt >> 1) == 1) ? 128 : 0) + (kt & 1) * 64;
            return *reinterpret_cast<const bf16x8*>(erow[c] + off);
        } else {
            const int p = (kt >= 12) ? 2 : (kt >= 6 ? 1 : 0);
            const int ktm = kt - p * 6;
            const bool lo = (p == 1);
            if (ktm < 2)
                return *reinterpret_cast<const bf16x8*>(erow[c] + (lo ? 128 : 0) + ktm * 64);
            const unsigned short* hp = lo ? hrlo[c] : hrhi[c];
            return *reinterpret_cast<const bf16x8*>(hp + (ktm - 2) * 64);
        }
    };

    f32x4 acc[4][NFC];
    #pragma unroll
    for (int a = 0; a < 4; ++a)
        #pragma unroll
        for (int b = 0; b < NFC; ++b) acc[a][b] = (f32x4){0.f, 0.f, 0.f, 0.f};

    const int lane = tid & 63;
    const int wv = tid >> 6;
    const int wm = wv >> 2, wn = wv & 3;
    const int l15 = lane & 15, l4 = lane >> 4;

    bf16x8 aR0 = loadA(0, 0), aR1 = loadA(0, 1);
    bf16x8 bR[NBC];
    #pragma unroll
    for (int it = 0; it < NBC; ++it)
        bR[it] = *reinterpret_cast<const bf16x8*>(bsrc[it]);

    int cur = 0;
    for (int kt = 0; kt < KT; ++kt) {
        *reinterpret_cast<bf16x8*>(&Als[cur][adst[0]]) = aR0;
        *reinterpret_cast<bf16x8*>(&Als[cur][adst[1]]) = aR1;
        #pragma unroll
        for (int it = 0; it < NBC; ++it)
            *reinterpret_cast<bf16x8*>(&Bls[cur][bdst[it]]) = bR[it];
        if (kt + 1 < KT) {
            aR0 = loadA(kt + 1, 0);
            aR1 = loadA(kt + 1, 1);
            #pragma unroll
            for (int it = 0; it < NBC; ++it)
                bR[it] = *reinterpret_cast<const bf16x8*>(bsrc[it] + (size_t)(kt + 1) * 64);
        }
        __syncthreads();
        #pragma unroll
        for (int st = 0; st < 2; ++st) {
            const int q = st * 4 + l4;
            bf16x8 af[4];
            #pragma unroll
            for (int fm = 0; fm < 4; ++fm) {
                const int row = wm * 64 + fm * 16 + l15;
                af[fm] = *reinterpret_cast<const bf16x8*>(&Als[cur][row * 64 + ((q ^ (row & 7)) << 3)]);
            }
            #pragma unroll
            for (int fc = 0; fc < NFC; ++fc) {
                const int col = wn * (NCOL / 4) + fc * 16 + l15;
                const bf16x8 bfr = *reinterpret_cast<const bf16x8*>(&Bls[cur][col * 64 + ((q ^ (col & 7)) << 3)]);
                #pragma unroll
                for (int fm = 0; fm < 4; ++fm)
                    acc[fm][fc] = __builtin_amdgcn_mfma_f32_16x16x32_bf16(af[fm], bfr, acc[fm][fc], 0, 0, 0);
            }
        }
        cur ^= 1;
    }

    // ---- fused epilogue (gate-mates same-lane: fc, fc+2, fc+4), guarded stores ----
    #pragma unroll
    for (int fcL = 0; fcL < 2; ++fcL) {
        const int j = wn * 32 + fcL * 16 + l15;
        if constexpr (MODE == 0) {
            const float bff = b_f[j];
            #pragma unroll
            for (int fm = 0; fm < 4; ++fm) {
                #pragma unroll
                for (int r = 0; r < 4; ++r) {
                    const int rowl = wm * 64 + fm * 16 + l4 * 4 + r;
                    if (rowl >= vrows) continue;
                    const int node = nbase + rowl;
                    const size_t crow = (size_t)(seg.hcOff + node) * 128;
                    const size_t cbase = (size_t)(seg.hcOff + 2 * node - seg.N - 1) * 128;
                    const float fa = fast_sig(acc[fm][fcL][r] + bff);
                    const float fb = fast_sig(acc[fm][fcL + 2][r] + bff);
                    cbuf[crow + j] = fa * cbuf[cbase + j] + fb * cbuf[cbase + 128 + j];
                }
            }
        } else {
            const float bi = b_iou[j];
            const float bo = b_iou[128 + j];
            const float bu = b_iou[256 + j];
            #pragma unroll
            for (int fm = 0; fm < 4; ++fm) {
                #pragma unroll
                for (int r = 0; r < 4; ++r) {
                    const int rowl = wm * 64 + fm * 16 + l4 * 4 + r;
                    if (rowl >= vrows) continue;
                    const int node = nbase + rowl;
                    const size_t crow = (size_t)(seg.hcOff + node) * 128;
                    const float iv = fast_sig(acc[fm][fcL][r] + bi);
                    const float ov = fast_sig(acc[fm][fcL + 2][r] + bo);
                    const float uv = fast_tanh(acc[fm][fcL + 4][r] + bu);
                    float cn = iv * uv;
                    if (MODE == 1) cn += cbuf[crow + j];
                    cbuf[crow + j] = cn;
                    const float hn = ov * fast_tanh(cn);
                    const unsigned short hi16 = f2bf(hn);
                    whhi[crow + j] = hi16;
                    whlo[crow + j] = f2bf(hn - bf2f(hi16));
                }
            }
        }
    }
}

// ---------------- fp32 path (levels 6..11), per-level dispatch ----------------
template<int NP>
__global__ __launch_bounds__(128, 2)
void level_kernel(const float* __restrict__ emb,
                  const float* __restrict__ b_iou, const float* __restrict__ b_f,
                  const int* __restrict__ feat0, const int* __restrict__ feat1,
                  const int* __restrict__ feat2,
                  const unsigned short* __restrict__ hhi, const unsigned short* __restrict__ hlo,
                  unsigned short* __restrict__ whhi, unsigned short* __restrict__ whlo,
                  float* __restrict__ cbuf,
                  TreeSeg s0, TreeSeg s1, TreeSeg s2,
                  int blocks0, int blocks01)
{
    __shared__ float xe[NP][128];
    __shared__ float ha[NP][128];
    __shared__ float hb[NP][128];

    const int bid = blockIdx.x;
    TreeSeg seg; const int* feat; int batch;
    if (bid < blocks0)       { seg = s0; feat = feat0; batch = bid; }
    else if (bid < blocks01) { seg = s1; feat = feat1; batch = bid - blocks0; }
    else                     { seg = s2; feat = feat2; batch = bid - blocks01; }

    const int tid = threadIdx.x;
    const int nbase = seg.start + batch * NP;
    const int nval  = min(NP, seg.start + seg.cnt - nbase);

    for (int idx = tid; idx < NP * 32; idx += 128) {
        const int n  = idx >> 5;
        const int k4 = idx & 31;
        const int node = nbase + min(n, nval - 1);
        const int f = feat[node];
        float4 v = reinterpret_cast<const float4*>(emb + (size_t)f * 128)[k4];
        *reinterpret_cast<float4*>(&xe[n][k4 * 4]) = v;
        const int a = 2 * node - seg.N - 1;
        const size_t ra = (size_t)(seg.hcOff + a) * 128 + k4 * 4;
        ushort4 h4 = *reinterpret_cast<const ushort4*>(hhi + ra);
        ushort4 l4v = *reinterpret_cast<const ushort4*>(hlo + ra);
        float4 va;
        va.x = bf2f(h4.x) + bf2f(l4v.x);
        va.y = bf2f(h4.y) + bf2f(l4v.y);
        va.z = bf2f(h4.z) + bf2f(l4v.z);
        va.w = bf2f(h4.w) + bf2f(l4v.w);
        *reinterpret_cast<float4*>(&ha[n][k4 * 4]) = va;
        ushort4 h4b = *reinterpret_cast<const ushort4*>(hhi + ra + 128);
        ushort4 l4b = *reinterpret_cast<const ushort4*>(hlo + ra + 128);
        float4 vb;
        vb.x = bf2f(h4b.x) + bf2f(l4b.x);
        vb.y = bf2f(h4b.y) + bf2f(l4b.y);
        vb.z = bf2f(h4b.z) + bf2f(l4b.z);
        vb.w = bf2f(h4b.w) + bf2f(l4b.w);
        *reinterpret_cast<float4*>(&hb[n][k4 * 4]) = vb;
    }
    __syncthreads();

    const int j = tid;
    float ai[NP], ao[NP], au[NP], axf[NP], afa[NP], afb[NP];
    {
        const float bi = b_iou[j];
        const float bo = b_iou[128 + j];
        const float bu = b_iou[256 + j];
        const float bff = b_f[j];
        #pragma unroll
        for (int n = 0; n < NP; ++n) {
            ai[n] = bi; ao[n] = bo; au[n] = bu;
            axf[n] = bff; afa[n] = 0.0f; afb[n] = 0.0f;
        }
    }
    const float* pkj = g_pack + (size_t)j * 8;
    for (int kk = 0; kk < 32; ++kk) {
        float4 wa[4], wb[4];
        #pragma unroll
        for (int r = 0; r < 4; ++r) {
            const float* p = pkj + (size_t)(kk * 4 + r) * 1024;
            wa[r] = *reinterpret_cast<const float4*>(p);
            wb[r] = *reinterpret_cast<const float4*>(p + 4);
        }
        #pragma unroll
        for (int n = 0; n < NP; ++n) {
            const float4 xv = *reinterpret_cast<const float4*>(&xe[n][kk * 4]);
            const float4 av = *reinterpret_cast<const float4*>(&ha[n][kk * 4]);
            const float4 bv = *reinterpret_cast<const float4*>(&hb[n][kk * 4]);
            const float xs[4] = {xv.x, xv.y, xv.z, xv.w};
            const float as[4] = {av.x, av.y, av.z, av.w};
            const float bs[4] = {bv.x, bv.y, bv.z, bv.w};
            #pragma unroll
            for (int r = 0; r < 4; ++r) {
                const float hs = as[r] + bs[r];
                ai[n]  = fmaf(xs[r], wa[r].x, ai[n]);
                ao[n]  = fmaf(xs[r], wa[r].y, ao[n]);
                au[n]  = fmaf(xs[r], wa[r].z, au[n]);
                ai[n]  = fmaf(hs,    wb[r].x, ai[n]);
                ao[n]  = fmaf(hs,    wb[r].y, ao[n]);
                au[n]  = fmaf(hs,    wb[r].z, au[n]);
                axf[n] = fmaf(xs[r], wa[r].w, axf[n]);
                afa[n] = fmaf(as[r], wb[r].w, afa[n]);
                afb[n] = fmaf(bs[r], wb[r].w, afb[n]);
            }
        }
    }
    #pragma unroll
    for (int n = 0; n < NP; ++n) {
        if (n >= nval) break;
        const int node = nbase + n;
        const float iv = fast_sig(ai[n]);
        const float ov = fast_sig(ao[n]);
        const float uv = fast_tanh(au[n]);
        const float fav = fast_sig(axf[n] + afa[n]);
        const float fbv = fast_sig(axf[n] + afb[n]);
        const int a = 2 * node - seg.N - 1;
        const float ca  = cbuf[(size_t)(seg.hcOff + a) * 128 + j];
        const float cb2 = cbuf[(size_t)(seg.hcOff + a + 1) * 128 + j];
        const float cn = fmaf(fav, ca, fmaf(fbv, cb2, iv * uv));
        const float hn = ov * fast_tanh(cn);
        const size_t o = (size_t)(seg.hcOff + node) * 128 + j;
        cbuf[o] = cn;
        const unsigned short hi16 = f2bf(hn);
        whhi[o] = hi16;
        whlo[o] = f2bf(hn - bf2f(hi16));
    }
}

// ---------------- deep tail: cube levels 12..16 in ONE workgroup ----------------
// 512 threads = 4 sub-blocks of 128; __syncthreads is the only inter-level barrier.
__global__ __launch_bounds__(512)
void deep_kernel(const float* __restrict__ emb,
                 const float* __restrict__ b_iou, const float* __restrict__ b_f,
                 const int* __restrict__ feat0,
                 unsigned short* __restrict__ hhi, unsigned short* __restrict__ hlo,
                 float* __restrict__ cbuf)
{
    __shared__ float xe[4][4][128];
    __shared__ float ha[4][4][128];
    __shared__ float hb[4][4][128];

    const int tid = threadIdx.x;
    const int sub = tid >> 7;
    const int j = tid & 127;
    const int Ntree = 131071;

    for (int l = 12; l <= 16; ++l) {
        const int cnt = 1 << (16 - l);
        const int st  = Ntree - (1 << (17 - l)) + 1;
        const int nch = (cnt + 3) >> 2;     // 4,2,1,1,1 -> one pass always
        const int nbase = st + sub * 4;
        const int nval = (sub < nch) ? min(4, st + cnt - nbase) : 0;

        if (nval > 0) {
            // stage 4 nodes: exactly one float4 per thread per array
            const int n = j >> 5, k4 = j & 31;
            const int node = nbase + min(n, nval - 1);
            const int f = feat0[node];
            float4 v = reinterpret_cast<const float4*>(emb + (size_t)f * 128)[k4];
            *reinterpret_cast<float4*>(&xe[sub][n][k4 * 4]) = v;
            const int a = 2 * node - Ntree - 1;
            const size_t ra = (size_t)a * 128 + k4 * 4;
            ushort4 h4 = *reinterpret_cast<const ushort4*>(hhi + ra);
            ushort4 l4v = *reinterpret_cast<const ushort4*>(hlo + ra);
            float4 va;
            va.x = bf2f(h4.x) + bf2f(l4v.x);
            va.y = bf2f(h4.y) + bf2f(l4v.y);
            va.z = bf2f(h4.z) + bf2f(l4v.z);
            va.w = bf2f(h4.w) + bf2f(l4v.w);
            *reinterpret_cast<float4*>(&ha[sub][n][k4 * 4]) = va;
            ushort4 h4b = *reinterpret_cast<const ushort4*>(hhi + ra + 128);
            ushort4 l4b = *reinterpret_cast<const ushort4*>(hlo + ra + 128);
            float4 vb;
            vb.x = bf2f(h4b.x) + bf2f(l4b.x);
            vb.y = bf2f(h4b.y) + bf2f(l4b.y);
            vb.z = bf2f(h4b.z) + bf2f(l4b.z);
            vb.w = bf2f(h4b.w) + bf2f(l4b.w);
            *reinterpret_cast<float4*>(&hb[sub][n][k4 * 4]) = vb;
        }
        __syncthreads();

        if (nval > 0) {
            float ai[4], ao[4], au[4], axf[4], afa[4], afb[4];
            {
                const float bi = b_iou[j];
                const float bo = b_iou[128 + j];
                const float bu = b_iou[256 + j];
                const float bff = b_f[j];
                #pragma unroll
                for (int n = 0; n < 4; ++n) {
                    ai[n] = bi; ao[n] = bo; au[n] = bu;
                    axf[n] = bff; afa[n] = 0.0f; afb[n] = 0.0f;
                }
            }
            const float* pkj = g_pack + (size_t)j * 8;
            for (int kk = 0; kk < 32; ++kk) {
                float4 wa[4], wb[4];
                #pragma unroll
                for (int r = 0; r < 4; ++r) {
                    const float* p = pkj + (size_t)(kk * 4 + r) * 1024;
                    wa[r] = *reinterpret_cast<const float4*>(p);
                    wb[r] = *reinterpret_cast<const float4*>(p + 4);
                }
                #pragma unroll
                for (int n = 0; n < 4; ++n) {
                    const float4 xv = *reinterpret_cast<const float4*>(&xe[sub][n][kk * 4]);
                    const float4 av = *reinterpret_cast<const float4*>(&ha[sub][n][kk * 4]);
                    const float4 bv = *reinterpret_cast<const float4*>(&hb[sub][n][kk * 4]);
                    const float xs[4] = {xv.x, xv.y, xv.z, xv.w};
                    const float as[4] = {av.x, av.y, av.z, av.w};
                    const float bs[4] = {bv.x, bv.y, bv.z, bv.w};
                    #pragma unroll
                    for (int r = 0; r < 4; ++r) {
                        const float hs = as[r] + bs[r];
                        ai[n]  = fmaf(xs[r], wa[r].x, ai[n]);
                        ao[n]  = fmaf(xs[r], wa[r].y, ao[n]);
                        au[n]  = fmaf(xs[r], wa[r].z, au[n]);
                        ai[n]  = fmaf(hs,    wb[r].x, ai[n]);
                        ao[n]  = fmaf(hs,    wb[r].y, ao[n]);
                        au[n]  = fmaf(hs,    wb[r].z, au[n]);
                        axf[n] = fmaf(xs[r], wa[r].w, axf[n]);
                        afa[n] = fmaf(as[r], wb[r].w, afa[n]);
                        afb[n] = fmaf(bs[r], wb[r].w, afb[n]);
                    }
                }
            }
            #pragma unroll
            for (int n = 0; n < 4; ++n) {
                if (n >= nval) break;
                const int node = nbase + n;
                const float iv = fast_sig(ai[n]);
                const float ov = fast_sig(ao[n]);
                const float uv = fast_tanh(au[n]);
                const float fav = fast_sig(axf[n] + afa[n]);
                const float fbv = fast_sig(axf[n] + afb[n]);
                const int a = 2 * node - Ntree - 1;
                const float ca  = cbuf[(size_t)a * 128 + j];
                const float cb2 = cbuf[(size_t)(a + 1) * 128 + j];
                const float cn = fmaf(fav, ca, fmaf(fbv, cb2, iv * uv));
                const float hn = ov * fast_tanh(cn);
                const size_t o = (size_t)node * 128 + j;
                cbuf[o] = cn;
                const unsigned short hi16 = f2bf(hn);
                hhi[o] = hi16;
                hlo[o] = f2bf(hn - bf2f(hi16));
            }
        }
        __syncthreads();
    }
}

// fuse_a_b @ h_c == h_a * dot(h_b, h_c); then 2-layer MLP with ReLU.
__global__ __launch_bounds__(128)
void final_kernel(const unsigned short* __restrict__ hhi, const unsigned short* __restrict__ hlo,
                  const float* __restrict__ fc1_w, const float* __restrict__ fc1_b,
                  const float* __restrict__ fc2_w, const float* __restrict__ fc2_b,
                  float* __restrict__ out,
                  int rc, int ra, int rb)
{
    __shared__ float sh[128];
    __shared__ float z1[64];
    __shared__ float dots[2];
    const int tid = threadIdx.x;

    const float hc  = bf2f(hhi[(size_t)rc * H + tid]) + bf2f(hlo[(size_t)rc * H + tid]);
    const float hav = bf2f(hhi[(size_t)ra * H + tid]) + bf2f(hlo[(size_t)ra * H + tid]);
    const float hbv = bf2f(hhi[(size_t)rb * H + tid]) + bf2f(hlo[(size_t)rb * H + tid]);

    float p = hbv * hc;
    #pragma unroll
    for (int o = 32; o > 0; o >>= 1) p += __shfl_down(p, o);
    if ((tid & 63) == 0) dots[tid >> 6] = p;
    __syncthreads();
    const float dot = dots[0] + dots[1];
    sh[tid] = hav * dot;
    __syncthreads();

    if (tid < 64) {
        float z = fc1_b[tid];
        for (int i = 0; i < 128; ++i) z = fmaf(sh[i], fc1_w[i * 64 + tid], z);
        z1[tid] = fmaxf(z, 0.0f);
    }
    __syncthreads();
    if (tid < 3) {
        float z = fc2_b[tid];
        for (int jj = 0; jj < 64; ++jj) z = fmaf(z1[jj], fc2_w[jj * 3 + tid], z);
        out[tid] = fmaxf(z, 0.0f);
    }
}

extern "C" void kernel_launch(void* const* d_in, const int* in_sizes, int n_in,
                              void* d_out, int out_size, void* d_ws, size_t ws_size,
                              hipStream_t stream) {
    const float* emb   = (const float*)d_in[12];
    const float* W_iou = (const float*)d_in[13];
    const float* b_iou = (const float*)d_in[14];
    const float* U_iou = (const float*)d_in[15];
    const float* W_f   = (const float*)d_in[16];
    const float* b_f   = (const float*)d_in[17];
    const float* U_f   = (const float*)d_in[18];
    const float* fc1_w = (const float*)d_in[19];
    const float* fc1_b = (const float*)d_in[20];
    const float* fc2_w = (const float*)d_in[21];
    const float* fc2_b = (const float*)d_in[22];
    const int* feats[3] = { (const int*)d_in[0], (const int*)d_in[4], (const int*)d_in[8] };

    const int D[3] = {17, 12, 12};
    const int N[3] = {131071, 4095, 4095};
    const int off[3] = {0, 131071, 131071 + 4095};

    float* cbuf = (float*)d_ws;
    unsigned short* hhi = (unsigned short*)(cbuf + (size_t)NTOT * 128);
    unsigned short* hlo = hhi + (size_t)NTOT * 128;

    pack_kernel<<<128, 128, 0, stream>>>(W_iou, W_f, U_iou, U_f);
    {
        const int NB3 = 384 * 1152 + 256 * 1152 + 384 * 384;
        pack_B<<<(NB3 + 255) / 256, 256, 0, stream>>>(W_iou, U_iou, W_f, U_f);
    }
    pack_emb<<<(VOCAB * 32 + 255) / 256, 256, 0, stream>>>(emb);

    auto mkseg = [&](int l, int t) {
        TreeSeg s;
        if (l <= D[t] - 1) {
            s.cnt   = 1 << (D[t] - 1 - l);
            s.start = N[t] - (1 << (D[t] - l)) + 1;
        } else { s.cnt = 0; s.start = 0; }
        s.hcOff = off[t]; s.N = N[t];
        return s;
    };

    // ---- leaf level (l=0): MFMA IOU-leaf ----
    {
        TreeSeg s0 = mkseg(0, 0), s1 = mkseg(0, 1), s2 = mkseg(0, 2);
        int b0 = (s0.cnt + 127) / 128, b1 = (s1.cnt + 127) / 128, b2 = (s2.cnt + 127) / 128;
        gemm_level<2><<<b0 + b1 + b2, 512, 0, stream>>>(
            feats[0], feats[1], feats[2], hhi, hlo, hhi, hlo, cbuf,
            b_iou, b_f, s0, s1, s2, b0, b0 + b1);
    }

    // ---- levels 1..5: MFMA F then IOU (masked 128-row blocks) ----
    for (int l = 1; l <= 5; ++l) {
        TreeSeg s0 = mkseg(l, 0), s1 = mkseg(l, 1), s2 = mkseg(l, 2);
        int b0 = (s0.cnt + 127) / 128, b1 = (s1.cnt + 127) / 128, b2 = (s2.cnt + 127) / 128;
        const int total = b0 + b1 + b2;
        gemm_level<0><<<total, 512, 0, stream>>>(
            feats[0], feats[1], feats[2], hhi, hlo, hhi, hlo, cbuf,
            b_iou, b_f, s0, s1, s2, b0, b0 + b1);
        gemm_level<1><<<total, 512, 0, stream>>>(
            feats[0], feats[1], feats[2], hhi, hlo, hhi, hlo, cbuf,
            b_iou, b_f, s0, s1, s2, b0, b0 + b1);
    }

    // ---- levels 6..11: fp32 per-level (NP=8) ----
    for (int l = 6; l <= 11; ++l) {
        TreeSeg s[3];
        int blocks[3];
        for (int t = 0; t < 3; ++t) {
            s[t] = mkseg(l, t);
            blocks[t] = (s[t].cnt + 7) / 8;
        }
        const int total = blocks[0] + blocks[1] + blocks[2];
        level_kernel<8><<<total, 128, 0, stream>>>(
            emb, b_iou, b_f, feats[0], feats[1], feats[2],
            hhi, hlo, hhi, hlo, cbuf,
            s[0], s[1], s[2], blocks[0], blocks[0] + blocks[1]);
    }

    // ---- cube levels 12..16: one workgroup, __syncthreads between levels ----
    deep_kernel<<<1, 512, 0, stream>>>(emb, b_iou, b_f, feats[0], hhi, hlo, cbuf);

    const int rc = off[0] + N[0] - 1;
    const int ra = off[1] + N[1] - 1;
    const int rb = off[2] + N[2] - 1;
    final_kernel<<<1, 128, 0, stream>>>(hhi, hlo, fc1_w, fc1_b, fc2_w, fc2_b,
                                        (float*)d_out, rc, ra, rb);
}